// Round 8
// baseline (299.157 us; speedup 1.0000x reference)
//
#include <hip/hip_runtime.h>
#include <hip/hip_bf16.h>

typedef __attribute__((ext_vector_type(8))) short  short8;
typedef __attribute__((ext_vector_type(4))) float  floatx4;

#define UH   2048    // U * H (row stride of inputs/hidden/out in floats)
#define XPAD 256     // NO pad: 512 B row stride; bank conflicts killed by XOR swizzle
                     // (2 bufs x 64 x 256 x 2B = 65536 B exactly -> 2 blocks/CU)

#define MFMA16(a,b,c) __builtin_amdgcn_mfma_f32_16x16x32_bf16(a, b, c, 0, 0, 0)

static __device__ __forceinline__ unsigned int pkbf16(float a, float b) {
    __hip_bfloat162 p = __float22bfloat162_rn(make_float2(a, b));
    return *(unsigned int*)&p;
}

// ---------------- fused GRU kernel (single dispatch, no prep) -----------------
// grid = 512 persistent, 512 threads (8 waves), TARGET 2 blocks/CU (LDS exactly
// 64 KiB/block). Block bx: u = ((bx&7)<<1)|((bx>>3)&1) (XCD-paired, W L2-
// resident); 4 m-tiles of 64 rows each. Wave wv owns output cols [16wv,16wv+16).
//
// r1 (76us, clean 136MB traffic) failed 2-block co-residency at 17.6% occupancy;
// suspected cause: XPAD=264 pushed LDS to 66KB which rounds past the allocation
// granule. This kernel is r1 with XPAD=256 (64KB exact) + XOR bank-swizzle
// byte ^= ((row&7)<<4) on all three LDS access sites (write mask = wv<<4,
// frag-read mask = (lr&7)<<4, hv-read mask = (m&7)<<4): 8 consecutive rows
// spread across all 32 banks, residual 2-way aliasing is free (m136).
__global__ __launch_bounds__(512, 4) void gru_fused(
    const float* __restrict__ inputs, const float* __restrict__ hidden,
    const float* __restrict__ w_ih,   const float* __restrict__ w_hh,
    const float* __restrict__ b_ih,   const float* __restrict__ b_hh,
    float* __restrict__ out)
{
    __shared__ __align__(16) __hip_bfloat16 Xs[2][64][XPAD];

    const int bx   = blockIdx.x;
    const int u    = ((bx & 7) << 1) | ((bx >> 3) & 1);  // XCD-local u pair
    const int mt0  = (bx >> 4) * 4;                      // first of 4 m-tiles
    const int tid  = threadIdx.x;
    const int lane = tid & 63;
    const int wv   = tid >> 6;     // [0,8): wave owns output cols [16*wv,16*wv+16)
    const int lr   = lane & 15;
    const int lq   = lane >> 4;

    // ---- W fragments: direct fp32 load + pack, once per block --------------
    // fragment (gt,s): lane elem j = W[u][gt*16+lr][s*32+lq*8+j],
    // W = [w_ih | w_hh] along k. 8 consecutive floats -> 2x float4.
    auto loadW = [&](int gt, int s) -> short8 {
        const int row = gt * 16 + lr;
        const int k0  = s * 32 + lq * 8;          // s<4 -> w_ih, s>=4 -> w_hh
        const float* src = (k0 < 128)
            ? (w_ih + (size_t)(u * 384 + row) * 128 + k0)
            : (w_hh + (size_t)(u * 384 + row) * 128 + (k0 - 128));
        float4 v0 = ((const float4*)src)[0];
        float4 v1 = ((const float4*)src)[1];
        union { uint4 q; short8 s8; } cvt;
        cvt.q.x = pkbf16(v0.x, v0.y);
        cvt.q.y = pkbf16(v0.z, v0.w);
        cvt.q.z = pkbf16(v1.x, v1.y);
        cvt.q.w = pkbf16(v1.z, v1.w);
        return cvt.s8;
    };
    short8 fR[8], fZ[8], fN[8];
    #pragma unroll
    for (int s = 0; s < 8; ++s) {
        fR[s] = loadW(     wv, s);
        fZ[s] = loadW( 8 + wv, s);
        fN[s] = loadW(16 + wv, s);
    }

    // ---- bias in registers (thread's output column is fixed) ----------------
    const int   c   = wv * 16 + lr;
    const float br  = b_ih[u * 384 +       c] + b_hh[u * 384 +       c];
    const float bz  = b_ih[u * 384 + 128 + c] + b_hh[u * 384 + 128 + c];
    const float bxn = b_ih[u * 384 + 256 + c];
    const float bhn = b_hh[u * 384 + 256 + c];

    // ---- staging geometry: thread loads 16B at col scol, rows wv + 8*i ------
    const int scol = (tid & 63) * 4;                   // float col in [0,256)
    const float* sbase = ((scol < 128) ? (inputs + scol)
                                       : (hidden + (scol - 128)))
                       + (size_t)u * 128;

    float4 stg[8];   // in-flight tile (32 VGPR)

    auto ISSUE = [&](int mt) {
        const float* p = sbase + (size_t)(mt * 64 + wv) * UH;
        #pragma unroll
        for (int i = 0; i < 8; ++i)
            stg[i] = *(const float4*)(p + (size_t)(i * 8) * UH);
    };
    // write rows i*8+wv at byte (lane*8) ^ (wv<<4)   [row&7 == wv]
    auto WRITE = [&](int buf) {
        #pragma unroll
        for (int i = 0; i < 8; ++i) {
            uint2 w;
            w.x = pkbf16(stg[i].x, stg[i].y);
            w.y = pkbf16(stg[i].z, stg[i].w);
            char* rowp = (char*)&Xs[buf][i * 8 + wv][0];
            *(uint2*)(rowp + ((lane * 8) ^ (wv << 4))) = w;
        }
    };
    auto BARRIER = [&]() {
        // drain LDS only; global prefetch loads stay in flight across barrier
        asm volatile("s_waitcnt lgkmcnt(0)" ::: "memory");
        __builtin_amdgcn_sched_barrier(0);
        __builtin_amdgcn_s_barrier();
        __builtin_amdgcn_sched_barrier(0);
    };

    // ---- prologue: fill buf0, launch tile1 loads ----------------------------
    ISSUE(mt0 + 0);
    WRITE(0);                 // vmcnt wait on stg inserted by compiler
    ISSUE(mt0 + 1);
    BARRIER();

    #pragma unroll 1
    for (int j = 0; j < 4; ++j) {
        const int buf = j & 1;

        // ---- compute tile j from Xs[buf] (B in registers / rematerialized) --
        floatx4 aR[4], aZ[4], aXN[4], aHN[4];
        #pragma unroll
        for (int m4 = 0; m4 < 4; ++m4) {
            aR[m4]  = (floatx4){0.f, 0.f, 0.f, 0.f};
            aZ[m4]  = (floatx4){0.f, 0.f, 0.f, 0.f};
            aXN[m4] = (floatx4){0.f, 0.f, 0.f, 0.f};
            aHN[m4] = (floatx4){0.f, 0.f, 0.f, 0.f};
        }
        #pragma unroll
        for (int s = 0; s < 8; ++s) {
            short8 xF[4];
            #pragma unroll
            for (int m4 = 0; m4 < 4; ++m4) {
                const char* rowp = (const char*)&Xs[buf][m4 * 16 + lr][0];
                xF[m4] = *(const short8*)(rowp
                           + ((s * 64 + lq * 16) ^ ((lr & 7) << 4)));
            }
            #pragma unroll
            for (int m4 = 0; m4 < 4; ++m4) {
                aR[m4] = MFMA16(xF[m4], fR[s], aR[m4]);
                aZ[m4] = MFMA16(xF[m4], fZ[s], aZ[m4]);
                if (s < 4) aXN[m4] = MFMA16(xF[m4], fN[s], aXN[m4]);
                else       aHN[m4] = MFMA16(xF[m4], fN[s], aHN[m4]);
            }
        }

        // ---- epilogue: C/D layout col = lane&15, row = quad*4 + reg ---------
        float* obase = out + (size_t)(mt0 + j) * 64 * UH + u * 128 + c;
        #pragma unroll
        for (int m4 = 0; m4 < 4; ++m4) {
            #pragma unroll
            for (int r = 0; r < 4; ++r) {
                const int m = m4 * 16 + lq * 4 + r;
                float rv = __builtin_amdgcn_rcpf(1.f + __expf(-(aR[m4][r] + br)));
                float zv = __builtin_amdgcn_rcpf(1.f + __expf(-(aZ[m4][r] + bz)));
                float npre = (aXN[m4][r] + bxn) + rv * (aHN[m4][r] + bhn);
                float nv = 2.f * __builtin_amdgcn_rcpf(1.f + __expf(-2.f * npre)) - 1.f; // tanh
                const char* rowp = (const char*)&Xs[buf][m][0];
                float hv = __bfloat162float(*(const __hip_bfloat16*)(rowp
                             + ((256 + 2 * c) ^ ((m & 7) << 4))));  // original hidden
                obase[(size_t)m * UH] = nv + zv * (hv - nv);
            }
        }

        // ---- pipeline: land tile j+1 into the other buffer, launch tile j+2 -
        if (j < 3) {
            WRITE(buf ^ 1);                  // waits only on its own stg vmcnt
            if (j < 2) ISSUE(mt0 + j + 2);   // fire-and-forget across barrier
            BARRIER();
        }
    }
}

// ---------------- launch ------------------------------------------------------

extern "C" void kernel_launch(void* const* d_in, const int* in_sizes, int n_in,
                              void* d_out, int out_size, void* d_ws, size_t ws_size,
                              hipStream_t stream) {
    const float* inputs = (const float*)d_in[0];
    const float* hidden = (const float*)d_in[1];
    const float* w_ih   = (const float*)d_in[2];
    const float* w_hh   = (const float*)d_in[3];
    const float* b_ih   = (const float*)d_in[4];
    const float* b_hh   = (const float*)d_in[5];
    float* out = (float*)d_out;

    gru_fused<<<dim3(512), dim3(512), 0, stream>>>(inputs, hidden,
                                                   w_ih, w_hh, b_ih, b_hh, out);
}

// Round 9
// 203.742 us; speedup vs baseline: 1.4683x; 1.4683x over previous
//
#include <hip/hip_runtime.h>
#include <hip/hip_bf16.h>

typedef __attribute__((ext_vector_type(8))) short  short8;
typedef __attribute__((ext_vector_type(4))) float  floatx4;

#define UH   2048    // U * H (row stride of inputs/hidden/out in floats)
#define XPAD 256     // 512 B row stride, NO pad: LDS = 64*256*2 = 32768 B exact
                     // (32 KB granule -> 2+ blocks/CU); banks fixed by XOR swizzle

#define MFMA16(a,b,c) __builtin_amdgcn_mfma_f32_16x16x32_bf16(a, b, c, 0, 0, 0)

static __device__ __forceinline__ unsigned int pkbf16(float a, float b) {
    __hip_bfloat162 p = __float22bfloat162_rn(make_float2(a, b));
    return *(unsigned int*)&p;
}
static __device__ __forceinline__ float bf2f(unsigned short h) {
    unsigned int u = (unsigned int)h << 16;
    return *(float*)&u;
}

// ---------------- prep kernel (round-0 proven) --------------------------------
// Wc in MFMA-fragment order: fragment id = (u*24 + gt)*8 + s  (gt = 16-gate tile,
// s = k-step). Element lane*8+j = W[u][gt*16+(lane&15)][s*32+(lane>>4)*8+j],
// k<128 -> w_ih, else w_hh.
// blocks [0,768): weights; [768,800): bias_c[u][512]
__global__ __launch_bounds__(256) void prep(const float* __restrict__ w_ih,
                                            const float* __restrict__ w_hh,
                                            const float* __restrict__ b_ih,
                                            const float* __restrict__ b_hh,
                                            __hip_bfloat16* __restrict__ Wc,
                                            float* __restrict__ bias_c) {
    if (blockIdx.x < 768) {
        int t   = blockIdx.x * 256 + threadIdx.x;   // [0, 196608)
        int k8  = t & 31;                           // 8-float chunk within row
        int row = t >> 5;                           // u*384 + g
        int u   = row / 384;
        int g   = row - u * 384;
        int k   = k8 * 8;
        const float* src = (k < 128) ? (w_ih + (size_t)row * 128 + k)
                                     : (w_hh + (size_t)row * 128 + (k - 128));
        float4 v0 = ((const float4*)src)[0];
        float4 v1 = ((const float4*)src)[1];
        uint4 w;
        w.x = pkbf16(v0.x, v0.y);
        w.y = pkbf16(v0.z, v0.w);
        w.z = pkbf16(v1.x, v1.y);
        w.w = pkbf16(v1.z, v1.w);
        int gt = g >> 4, lr = g & 15;
        int s  = k8 >> 2, lq = k8 & 3;
        size_t off = (size_t)((u * 24 + gt) * 8 + s) * 512 + (lq * 16 + lr) * 8;
        *(uint4*)(Wc + off) = w;
    } else {
        int idx = (blockIdx.x - 768) * 256 + threadIdx.x;   // [0, 8192)
        int u = idx >> 9;
        int g = idx & 511;
        float v;
        if (g < 256)       v = b_ih[u * 384 + g] + b_hh[u * 384 + g];
        else if (g < 384)  v = b_ih[u * 384 + g];          // xn bias
        else               v = b_hh[u * 384 + (g - 128)];  // hn bias
        bias_c[idx] = v;
    }
}

// ---------------- fused GRU kernel --------------------------------------------
// 2048 ONE-SHOT blocks x 512 threads (8 waves), one 64-row tile per block.
// Footprint law (r0..r8 evidence): traffic is clean (~136 MB) iff the resident
// block set covers <= ~half the problem. Short-lived blocks give a sliding
// half-window (r0-proven clean); granule-exact 32 KB LDS + lean registers give
// 2+ true blocks/CU (r8-proven) so staging of incoming blocks overlaps compute
// of resident ones.
//   - W frags streamed from L2-resident Wc (u XCD-paired) -> VGPR 64.
//   - Swapped-D MFMA (A=W, B=X): lane l, reg r -> row m = (l&15)+16*m4,
//     col c = (l>>4)*4+r+16*wv => coalesced float4 stores, bias in acc init.
//   - XOR bank swizzle byte ^= ((row&7)<<4) on all LDS accesses (write mask
//     wv<<4, frag/hv read mask (lr&7)<<4): 512 B row stride conflict-free.
//   - hv from LDS tile (r5-verified math, absmax 0.03125).
__global__ __launch_bounds__(512, 4) void gru_fused(
    const float* __restrict__ inputs, const float* __restrict__ hidden,
    const __hip_bfloat16* __restrict__ Wc, const float* __restrict__ bias_c,
    float* __restrict__ out)
{
    __shared__ __align__(16) __hip_bfloat16 Xs[64][XPAD];   // 32768 B exact

    const int bx   = blockIdx.x;                        // [0,2048)
    const int u    = ((bx & 7) << 1) | ((bx >> 3) & 1); // XCD-local u pair
    const int rowb = (bx >> 4) * 64;                    // this block's 64 rows
    const int tid  = threadIdx.x;
    const int lane = tid & 63;
    const int wv   = tid >> 6;      // [0,8): wave owns output cols [16*wv,16*wv+16)
    const int lr   = lane & 15;
    const int lq   = lane >> 4;

    // ---- bias -> accumulator init (thread covers cols c0..c0+3) -------------
    const int c0 = wv * 16 + lq * 4;
    const floatx4 accR0  = *(const floatx4*)(bias_c + u * 512 +       c0);
    const floatx4 accZ0  = *(const floatx4*)(bias_c + u * 512 + 128 + c0);
    const floatx4 accXN0 = *(const floatx4*)(bias_c + u * 512 + 256 + c0);
    const floatx4 accHN0 = *(const floatx4*)(bias_c + u * 512 + 384 + c0);

    // ---- stage X = [inputs | hidden] (64 rows x 256 cols) fp32 -> bf16 LDS --
    // thread loads 16B at col scol for rows i*8+wv; write swizzled (row&7==wv)
    const int scol = lane * 4;                          // float col in [0,256)
    const float* sbase = ((scol < 128) ? (inputs + scol)
                                       : (hidden + (scol - 128)))
                       + (size_t)u * 128;
    {
        float4 stg[8];
        #pragma unroll
        for (int i = 0; i < 8; ++i)
            stg[i] = *(const float4*)(sbase + (size_t)(rowb + i * 8 + wv) * UH);
        #pragma unroll
        for (int i = 0; i < 8; ++i) {
            uint2 w;
            w.x = pkbf16(stg[i].x, stg[i].y);
            w.y = pkbf16(stg[i].z, stg[i].w);
            char* rowp = (char*)&Xs[i * 8 + wv][0];
            *(uint2*)(rowp + ((lane * 8) ^ (wv << 4))) = w;
        }
    }
    __syncthreads();

    // ---- compute: stream W frags from L2, X frags from LDS (swizzled) -------
    const short* WgU = (const short*)Wc + (size_t)u * 98304 + lane * 8;

    floatx4 aR[4]  = {accR0,  accR0,  accR0,  accR0};
    floatx4 aZ[4]  = {accZ0,  accZ0,  accZ0,  accZ0};
    floatx4 aXN[4] = {accXN0, accXN0, accXN0, accXN0};
    floatx4 aHN[4] = {accHN0, accHN0, accHN0, accHN0};

    #pragma unroll
    for (int s = 0; s < 8; ++s) {
        short8 bR = *(const short8*)(WgU + (size_t)(      wv * 8 + s) * 512);
        short8 bZ = *(const short8*)(WgU + (size_t)( 64 + wv * 8 + s) * 512);
        short8 bN = *(const short8*)(WgU + (size_t)(128 + wv * 8 + s) * 512);
        #pragma unroll
        for (int m4 = 0; m4 < 4; ++m4) {
            const char* rowp = (const char*)&Xs[m4 * 16 + lr][0];
            short8 xF = *(const short8*)(rowp
                          + ((s * 64 + lq * 16) ^ ((lr & 7) << 4)));
            aR[m4] = MFMA16(bR, xF, aR[m4]);
            aZ[m4] = MFMA16(bZ, xF, aZ[m4]);
            if (s < 4) aXN[m4] = MFMA16(bN, xF, aXN[m4]);
            else       aHN[m4] = MFMA16(bN, xF, aHN[m4]);
        }
    }

    // ---- epilogue: thread owns (m = m4*16+lr, cols c0..c0+3) ----------------
    #pragma unroll
    for (int m4 = 0; m4 < 4; ++m4) {
        const int mloc = m4 * 16 + lr;
        const char* rowp = (const char*)&Xs[mloc][0];
        ushort4 hq = *(const ushort4*)(rowp + ((256 + 2 * c0) ^ ((lr & 7) << 4)));
        const unsigned short hs[4] = {hq.x, hq.y, hq.z, hq.w};
        float4 o;
        float* op = (float*)&o;
        #pragma unroll
        for (int r = 0; r < 4; ++r) {
            float rv = __builtin_amdgcn_rcpf(1.f + __expf(-aR[m4][r]));
            float zv = __builtin_amdgcn_rcpf(1.f + __expf(-aZ[m4][r]));
            float npre = aXN[m4][r] + rv * aHN[m4][r];
            float nv = 2.f * __builtin_amdgcn_rcpf(1.f + __expf(-2.f * npre)) - 1.f; // tanh
            float hv = bf2f(hs[r]);              // original hidden (bf16, LDS)
            op[r] = nv + zv * (hv - nv);
        }
        *(float4*)(out + (size_t)(rowb + mloc) * UH + u * 128 + c0) = o;
    }
}

// ---------------- launch ------------------------------------------------------

extern "C" void kernel_launch(void* const* d_in, const int* in_sizes, int n_in,
                              void* d_out, int out_size, void* d_ws, size_t ws_size,
                              hipStream_t stream) {
    const float* inputs = (const float*)d_in[0];
    const float* hidden = (const float*)d_in[1];
    const float* w_ih   = (const float*)d_in[2];
    const float* w_hh   = (const float*)d_in[3];
    const float* b_ih   = (const float*)d_in[4];
    const float* b_hh   = (const float*)d_in[5];
    float* out = (float*)d_out;

    __hip_bfloat16* Wc = (__hip_bfloat16*)d_ws;
    float* bias_c = (float*)((char*)d_ws + (size_t)16 * 384 * 256 * 2);  // +3,145,728 B

    prep<<<dim3(800), dim3(256), 0, stream>>>(w_ih, w_hh, b_ih, b_hh, Wc, bias_c);
    gru_fused<<<dim3(2048), dim3(512), 0, stream>>>(inputs, hidden, Wc, bias_c, out);
}